// Round 16
// baseline (10120.464 us; speedup 1.0000x reference)
//
#include <hip/hip_runtime.h>
#include <hip/hip_fp16.h>

#define B_  64
#define T_  2048
#define I_  64
#define H_  256
#define G4_ 1024   // 4*H

typedef _Float16 h2v __attribute__((ext_vector_type(2)));

__device__ __forceinline__ float fdot2(uint32_t a, uint32_t b, float c) {
#if __has_builtin(__builtin_amdgcn_fdot2)
    return __builtin_amdgcn_fdot2(__builtin_bit_cast(h2v, a), __builtin_bit_cast(h2v, b), c, false);
#else
    h2v ha = __builtin_bit_cast(h2v, a), hb = __builtin_bit_cast(h2v, b);
    return c + (float)ha.x * (float)hb.x + (float)ha.y * (float)hb.y;
#endif
}

__device__ __forceinline__ ushort f2h(float v) {
    return __builtin_bit_cast(ushort, (_Float16)v);
}
__device__ __forceinline__ float h2f(ushort v) {
    return (float)__builtin_bit_cast(_Float16, v);
}

// ---------------------------------------------------------------------------
// Repack W_hh fp32 [1024][256] -> f16 wpk[g][kc][h][j]  (g=gate, kc=K/8 chunk,
// h=hdim 0..255, j=0..7).  (r8 layout -- proven.)
// ---------------------------------------------------------------------------
__global__ void repack_kernel(const float* __restrict__ Whh, ushort* __restrict__ wpk) {
    int o  = blockIdx.x * 256 + threadIdx.x;   // 0 .. 262143
    int j  = o & 7;
    int h  = (o >> 3) & 255;
    int kc = (o >> 11) & 31;
    int g  = o >> 16;
    float v = Whh[(g * 256 + h) * 256 + kc * 8 + j];
    wpk[o] = f2h(v);
}

// ---------------------------------------------------------------------------
// gx2 = x @ W_ih^T + b_ih + b_hh, TRANSPOSED f16 layout [bt][hd][gate].
// Packed-f16 fdot2 inner loop (r14 -- proven).  grid = ((64*TCc)/32, 4).
// ---------------------------------------------------------------------------
__global__ __launch_bounds__(256) void gx_kernel(
    const float* __restrict__ x, const float* __restrict__ Wih,
    const float* __restrict__ bih, const float* __restrict__ bhh,
    ushort* __restrict__ gx2, int t0, int TCc) {

    __shared__ uint32_t xsp[32][32];            // 32 bt-rows x 32 f16-pairs
    const int bt0 = blockIdx.x * 32;
    const int gq  = blockIdx.y;                 // gate 0..3 (i,f,g,o)
    const int row = gq * 256 + threadIdx.x;     // W_ih row

    for (int i = threadIdx.x; i < 512; i += 256) {
        int r  = i >> 4, c4 = i & 15;
        int bt = bt0 + r;
        int b  = bt / TCc;
        int tl = bt - b * TCc;
        float4 v = *(const float4*)(&x[(((size_t)b * T_) + t0 + tl) * I_ + c4 * 4]);
        xsp[r][c4 * 2 + 0] = (uint32_t)f2h(v.x) | ((uint32_t)f2h(v.y) << 16);
        xsp[r][c4 * 2 + 1] = (uint32_t)f2h(v.z) | ((uint32_t)f2h(v.w) << 16);
    }
    __syncthreads();

    uint32_t wp[32];
#pragma unroll
    for (int k = 0; k < 32; ++k) {
        float a = Wih[row * I_ + 2 * k];
        float b = Wih[row * I_ + 2 * k + 1];
        wp[k] = (uint32_t)f2h(a) | ((uint32_t)f2h(b) << 16);
    }
    const float bias = bih[row] + bhh[row];

    for (int i = 0; i < 32; ++i) {
        float acc = bias;
#pragma unroll
        for (int k4 = 0; k4 < 8; ++k4) {
            uint4 xq = *(const uint4*)(&xsp[i][k4 * 4]);   // wave-uniform bcast
            acc = fdot2(wp[k4 * 4 + 0], xq.x, acc);
            acc = fdot2(wp[k4 * 4 + 1], xq.y, acc);
            acc = fdot2(wp[k4 * 4 + 2], xq.z, acc);
            acc = fdot2(wp[k4 * 4 + 3], xq.w, acc);
        }
        gx2[((size_t)(bt0 + i) * 256 + threadIdx.x) * 4 + gq] = f2h(acc);
    }
}

// ---------------------------------------------------------------------------
// Round-16: gate-split LSTM across 2 CUs per batch, RACE-FIXED.
// r15 tripwire diagnosis: partner could overwrite parts[step t] with step
// t+1 data before this block finished reading step t (no consume-ack).
// Fix: parts double-buffered by absolute-step parity.  Proof: role A's read
// of parity buffer P at step t happens-before A's flag release (t+2) at step
// t+1, which role B must acquire-observe (its step-t+1 spin) before its
// step-t+2 dot loop stores into P again.  Release/acquire closes the race
// with no extra critical-path sync.
// Block (role = bid>>6, b = bid&63): role 0 owns i,f; role 1 owns g,o; both
// full K=256, (hd, q=K-half) thread layout, weights 128 dw/thread, NO o-gate
// LDS stream (LDS ~3.5 KB).  Both roles redundantly run elementwise so h
// never crosses the wire.  Flags monotonic absolute-step, memset per launch.
// ---------------------------------------------------------------------------
__global__ __launch_bounds__(512, 1)
void lstm_kernel(
    const ushort* __restrict__ wpk, const ushort* __restrict__ gx2,
    ushort* __restrict__ hbuf,           // [B][T][H] f16 (full-T)
    float* __restrict__ state,           // [2][64][256]: c then h
    unsigned* __restrict__ flags,        // [2][64] absolute-step flags
    unsigned long long* __restrict__ parts,  // [2][2][64][256] (role,parity)
    int TCc, int t0, int first) {

    __shared__ __align__(16) ushort hs[256];     // h(t-1) as f16
    __shared__ __align__(16) float pex[256][2];  // q=1 -> q=0 partials

    const int tid   = threadIdx.x;
    const int hd    = tid & 255;
    const int q     = tid >> 8;        // K-half
    const int kbase = q << 4;
    const int role  = blockIdx.x >> 6; // 0: i,f   1: g,o
    const int b     = blockIdx.x & 63;
    const bool q0   = (q == 0);
    const int glo   = role * 2;
    const int ghi   = role * 2 + 1;

    // --- preload this role's 2 gate half-rows (128 dwords) ---
    uint32_t wa[64], wb[64];
#pragma unroll
    for (int k = 0; k < 16; ++k) {
        uint4 v = *(const uint4*)(wpk + (size_t)(glo * 32 + kbase + k) * 2048 + hd * 8);
        wa[k * 4 + 0] = v.x; wa[k * 4 + 1] = v.y; wa[k * 4 + 2] = v.z; wa[k * 4 + 3] = v.w;
    }
#pragma unroll
    for (int k = 0; k < 16; ++k) {
        uint4 v = *(const uint4*)(wpk + (size_t)(ghi * 32 + kbase + k) * 2048 + hd * 8);
        wb[k * 4 + 0] = v.x; wb[k * 4 + 1] = v.y; wb[k * 4 + 2] = v.z; wb[k * 4 + 3] = v.w;
    }

    float c = 0.f, h = 0.f;
    if (q0) {
        if (!first) {
            c = state[b * H_ + hd];
            h = state[B_ * H_ + b * H_ + hd];
        }
        hs[hd] = f2h(h);
    }
    __syncthreads();

    const ushort* gxb = gx2 + (size_t)b * TCc * G4_;
    ushort* hb = hbuf + (size_t)b * T_ * H_ + (size_t)t0 * H_;

    // parts index: ((role*2 + parity)*64 + b)*256 + hd ; parity stride 16384
    unsigned long long* pme = parts + (((size_t)role * 2) * 64 + b) * 256;
    unsigned long long* pot = parts + (((size_t)(role ^ 1) * 2) * 64 + b) * 256;
    unsigned* fme = flags + role * 64 + b;
    unsigned* fot = flags + (role ^ 1) * 64 + b;

    ushort4 cg;
    if (q0) cg = *(const ushort4*)(gxb + (size_t)0 * G4_ + hd * 4);

    for (int tl = 0; tl < TCc; ++tl) {
        const unsigned want = (unsigned)(t0 + tl + 1);
        const int par = (t0 + tl) & 1;           // parity buffer selector

        // prefetch next step's gates (q0; hidden under the dot loop)
        ushort4 ng;
        if (q0) {
            const int tn = (tl + 1 < TCc) ? tl + 1 : tl;
            ng = *(const ushort4*)(gxb + (size_t)tn * G4_ + hd * 4);
        }

        float a0 = 0.f, a1 = 0.f;    // this role's two gate partials
#pragma unroll
        for (int k = 0; k < 16; ++k) {
            const int kc = kbase + k;
            uint4 hq = *(const uint4*)(hs + kc * 8);     // wave-uniform bcast
            a0 = fdot2(wa[k * 4 + 0], hq.x, a0);
            a0 = fdot2(wa[k * 4 + 1], hq.y, a0);
            a0 = fdot2(wa[k * 4 + 2], hq.z, a0);
            a0 = fdot2(wa[k * 4 + 3], hq.w, a0);
            a1 = fdot2(wb[k * 4 + 0], hq.x, a1);
            a1 = fdot2(wb[k * 4 + 1], hq.y, a1);
            a1 = fdot2(wb[k * 4 + 2], hq.z, a1);
            a1 = fdot2(wb[k * 4 + 3], hq.w, a1);
        }

        if (!q0) { pex[hd][0] = a0; pex[hd][1] = a1; }
        __syncthreads();                              // B1: pex visible

        if (q0) {
            a0 += pex[hd][0];
            a1 += pex[hd][1];
            unsigned long long pk =
                (unsigned long long)__float_as_uint(a0) |
                ((unsigned long long)__float_as_uint(a1) << 32);
            __hip_atomic_store(&pme[par * 16384 + hd], pk,
                               __ATOMIC_RELAXED, __HIP_MEMORY_SCOPE_AGENT);
        }
        __syncthreads();                              // B2: stores drained (vmcnt)

        if (tid == 0) {
            __hip_atomic_store(fme, want, __ATOMIC_RELEASE, __HIP_MEMORY_SCOPE_AGENT);
            while (__hip_atomic_load(fot, __ATOMIC_ACQUIRE, __HIP_MEMORY_SCOPE_AGENT) < want) {}
        }
        __syncthreads();                              // B3: partner data ready

        if (q0) {
            unsigned long long pk =
                __hip_atomic_load(&pot[par * 16384 + hd],
                                  __ATOMIC_RELAXED, __HIP_MEMORY_SCOPE_AGENT);
            float p0 = __uint_as_float((unsigned)pk);
            float p1 = __uint_as_float((unsigned)(pk >> 32));
            float ai, af, ag, ao;
            if (role == 0) { ai = a0; af = a1; ag = p0; ao = p1; }
            else           { ag = a0; ao = a1; ai = p0; af = p1; }

            ai += h2f(cg.x); af += h2f(cg.y); ag += h2f(cg.z); ao += h2f(cg.w);

            float si = __builtin_amdgcn_rcpf(1.f + __expf(-ai));
            float sf = __builtin_amdgcn_rcpf(1.f + __expf(-af));
            float so = __builtin_amdgcn_rcpf(1.f + __expf(-ao));
            float eg = __expf(2.f * ag);
            float tg = (eg - 1.f) * __builtin_amdgcn_rcpf(eg + 1.f);
            c = sf * c + si * tg;
            float ec = __expf(2.f * c);
            float tc = (ec - 1.f) * __builtin_amdgcn_rcpf(ec + 1.f);
            h = so * tc;

            ushort hh = f2h(h);
            hs[hd] = hh;                     // both roles keep h locally
            if (role == 0) hb[(size_t)tl * H_ + hd] = hh;
            cg = ng;
        }
        __syncthreads();                              // B4: hs ready for next dot
    }

    if (q0 && role == 0) {
        state[b * H_ + hd]           = c;
        state[B_ * H_ + b * H_ + hd] = h;
    }
}

// ---------------------------------------------------------------------------
// out[b,t] = sum_hd h[b,t,hd] * Wo[hd] + bo.  Single launch over full T.
// ---------------------------------------------------------------------------
__global__ __launch_bounds__(256) void proj_kernel(
    const ushort* __restrict__ hbuf, const float* __restrict__ Wo,
    const float* __restrict__ bo, float* __restrict__ out) {

    const int lane = threadIdx.x & 63;
    const int wid  = blockIdx.x * 4 + (threadIdx.x >> 6);
    const int nw   = gridDim.x * 4;
    const int rows = B_ * T_;

    float4 w = *(const float4*)(Wo + lane * 4);
    const float bov = bo[0];

    for (int r = wid; r < rows; r += nw) {
        const ushort* hp = hbuf + (size_t)r * H_ + lane * 4;
        ushort4 u = *(const ushort4*)hp;
        float p = h2f(u.x) * w.x + h2f(u.y) * w.y + h2f(u.z) * w.z + h2f(u.w) * w.w;
#pragma unroll
        for (int m = 1; m < 64; m <<= 1) p += __shfl_xor(p, m, 64);
        if (lane == 0) out[r] = p + bov;
    }
}

// ---------------------------------------------------------------------------
extern "C" void kernel_launch(void* const* d_in, const int* in_sizes, int n_in,
                              void* d_out, int out_size, void* d_ws, size_t ws_size,
                              hipStream_t stream) {
    const float* x   = (const float*)d_in[0];
    const float* Wih = (const float*)d_in[1];
    const float* Whh = (const float*)d_in[2];
    const float* bih = (const float*)d_in[3];
    const float* bhh = (const float*)d_in[4];
    const float* Wo  = (const float*)d_in[5];
    const float* bo  = (const float*)d_in[6];
    float* out = (float*)d_out;

    char* ws = (char*)d_ws;
    ushort*   wpk   = (ushort*)ws;                            // 512 KB
    float*    state = (float*)(ws + 512 * 1024);              // 128 KB
    unsigned* flags = (unsigned*)(ws + 640 * 1024);           // 4 KB (512 B used)
    unsigned long long* parts =
        (unsigned long long*)(ws + 644 * 1024);               // 2 MB (dbuf)
    ushort*   hbuf  = (ushort*)(ws + 2692 * 1024);            // 64 MB full-T h
    const size_t hbuf_bytes = (size_t)B_ * T_ * H_ * 2;
    char*     dyn   = ws + 2692 * 1024 + hbuf_bytes;          // gx2 chunks

    size_t fixed = 2692 * 1024 + hbuf_bytes;
    size_t avail = (ws_size > fixed) ? ws_size - fixed : 0;
    long long tcmax = (long long)(avail / ((size_t)B_ * G4_ * 2));
    // Cap chunks at 512 steps so gx2 (64MB) + hbuf stay L3-resident.
    int TC = (tcmax > 512) ? 512 : (int)tcmax;
    TC &= ~63;               // multiple of 64
    if (TC < 64) TC = 64;    // minimum viable chunk

    hipMemsetAsync(flags, 0, 4096, stream);   // flags must start < 1 each launch
    repack_kernel<<<1024, 256, 0, stream>>>(Whh, wpk);

    for (int t0 = 0; t0 < T_; t0 += TC) {
        int TCc = (T_ - t0 < TC) ? (T_ - t0) : TC;
        ushort* gxb = (ushort*)dyn;
        dim3 g1((B_ * TCc) / 32, 4);
        gx_kernel<<<g1, 256, 0, stream>>>(x, Wih, bih, bhh, gxb, t0, TCc);
        lstm_kernel<<<128, 512, 0, stream>>>(wpk, gxb, hbuf, state, flags, parts,
                                             TCc, t0, t0 == 0 ? 1 : 0);
    }
    proj_kernel<<<512, 256, 0, stream>>>(hbuf, Wo, bo, out);
    (void)in_sizes; (void)n_in; (void)out_size;
}

// Round 17
// 8204.499 us; speedup vs baseline: 1.2335x; 1.2335x over previous
//
#include <hip/hip_runtime.h>
#include <hip/hip_fp16.h>

#define B_  64
#define T_  2048
#define I_  64
#define H_  256
#define G4_ 1024   // 4*H

typedef _Float16 h2v __attribute__((ext_vector_type(2)));

__device__ __forceinline__ float fdot2(uint32_t a, uint32_t b, float c) {
#if __has_builtin(__builtin_amdgcn_fdot2)
    return __builtin_amdgcn_fdot2(__builtin_bit_cast(h2v, a), __builtin_bit_cast(h2v, b), c, false);
#else
    h2v ha = __builtin_bit_cast(h2v, a), hb = __builtin_bit_cast(h2v, b);
    return c + (float)ha.x * (float)hb.x + (float)ha.y * (float)hb.y;
#endif
}

__device__ __forceinline__ ushort f2h(float v) {
    return __builtin_bit_cast(ushort, (_Float16)v);
}
__device__ __forceinline__ float h2f(ushort v) {
    return (float)__builtin_bit_cast(_Float16, v);
}

// ---------------------------------------------------------------------------
// Repack W_hh fp32 [1024][256] -> f16 wpk2[kc=32][hd=256][g=4][j=8]:
// thread (hd,g) at tid=hd*4+g loads (kc*1024 + tid)*8 -- fully coalesced
// 16B/lane preload of its own gate row.
// ---------------------------------------------------------------------------
__global__ void repack_kernel(const float* __restrict__ Whh, ushort* __restrict__ wpk2) {
    int o  = blockIdx.x * 256 + threadIdx.x;   // 0 .. 262143
    int j  = o & 7;
    int g  = (o >> 3) & 3;
    int hd = (o >> 5) & 255;
    int kc = o >> 13;
    wpk2[o] = f2h(Whh[(g * 256 + hd) * 256 + kc * 8 + j]);
}

// ---------------------------------------------------------------------------
// gx2 = x @ W_ih^T + b_ih + b_hh, TRANSPOSED f16 layout [bt][hd][gate].
// Packed-f16 fdot2 inner loop (r14 -- proven).  grid = ((64*TCc)/32, 4).
// ---------------------------------------------------------------------------
__global__ __launch_bounds__(256) void gx_kernel(
    const float* __restrict__ x, const float* __restrict__ Wih,
    const float* __restrict__ bih, const float* __restrict__ bhh,
    ushort* __restrict__ gx2, int t0, int TCc) {

    __shared__ uint32_t xsp[32][32];            // 32 bt-rows x 32 f16-pairs
    const int bt0 = blockIdx.x * 32;
    const int gq  = blockIdx.y;                 // gate 0..3 (i,f,g,o)
    const int row = gq * 256 + threadIdx.x;     // W_ih row

    for (int i = threadIdx.x; i < 512; i += 256) {
        int r  = i >> 4, c4 = i & 15;
        int bt = bt0 + r;
        int b  = bt / TCc;
        int tl = bt - b * TCc;
        float4 v = *(const float4*)(&x[(((size_t)b * T_) + t0 + tl) * I_ + c4 * 4]);
        xsp[r][c4 * 2 + 0] = (uint32_t)f2h(v.x) | ((uint32_t)f2h(v.y) << 16);
        xsp[r][c4 * 2 + 1] = (uint32_t)f2h(v.z) | ((uint32_t)f2h(v.w) << 16);
    }
    __syncthreads();

    uint32_t wp[32];
#pragma unroll
    for (int k = 0; k < 32; ++k) {
        float a = Wih[row * I_ + 2 * k];
        float b = Wih[row * I_ + 2 * k + 1];
        wp[k] = (uint32_t)f2h(a) | ((uint32_t)f2h(b) << 16);
    }
    const float bias = bih[row] + bhh[row];

    for (int i = 0; i < 32; ++i) {
        float acc = bias;
#pragma unroll
        for (int k4 = 0; k4 < 8; ++k4) {
            uint4 xq = *(const uint4*)(&xsp[i][k4 * 4]);   // wave-uniform bcast
            acc = fdot2(wp[k4 * 4 + 0], xq.x, acc);
            acc = fdot2(wp[k4 * 4 + 1], xq.y, acc);
            acc = fdot2(wp[k4 * 4 + 2], xq.z, acc);
            acc = fdot2(wp[k4 * 4 + 3], xq.w, acc);
        }
        gx2[((size_t)(bt0 + i) * 256 + threadIdx.x) * 4 + gq] = f2h(acc);
    }
}

// ---------------------------------------------------------------------------
// Round-17: gate-parallel single-CU LSTM.  64 blocks x 1024 threads (16
// waves, 4/SIMD).  Thread (hd = tid>>2, g = tid&3) owns ONE gate over FULL
// K=256: weights = 128 dw/thread -- the register file (512KB) equals W_hh,
// so this is the minimum-overflow decomposition (~30 dw in AGPR, tax ~60
// cyc/wave -- vs the LDS/global weight streams of r3-r13 at 1000+ cyc).
// NO weight streaming.  LDS = 1KB hs double-buffer only.  hq reads are
// wave-uniform broadcasts.  The 4 gates of hd live in one lane QUAD ->
// gathered with 3 __shfl_xor + cndmask (no pex, no extra barrier);
// elementwise runs redundantly per quad (divergence-free).  1 barrier/step.
// ---------------------------------------------------------------------------
__global__ __launch_bounds__(1024, 4)
void lstm_kernel(
    const ushort* __restrict__ wpk2, const ushort* __restrict__ gx2,
    ushort* __restrict__ hbuf,     // [B][T][H] f16 (full-T)
    float* __restrict__ state,     // [2][64][256]: c then h
    int TCc, int t0, int first) {

    __shared__ __align__(16) ushort hs[2][256];  // h dbuf (f16)

    const int tid = threadIdx.x;
    const int g   = tid & 3;        // gate: 0=i 1=f 2=g 3=o
    const int hd  = tid >> 2;       // owned h-dim
    const int b   = blockIdx.x;

    // --- preload this thread's full gate row (32 x 16B, coalesced) ---
    uint32_t wv[128];
#pragma unroll
    for (int kc = 0; kc < 32; ++kc) {
        uint4 v = *(const uint4*)(wpk2 + ((size_t)kc * 1024 + tid) * 8);
        wv[kc * 4 + 0] = v.x; wv[kc * 4 + 1] = v.y;
        wv[kc * 4 + 2] = v.z; wv[kc * 4 + 3] = v.w;
    }

    float c = 0.f, h = 0.f;
    if (!first) {
        c = state[b * H_ + hd];          // quad-broadcast loads
        h = state[B_ * H_ + b * H_ + hd];
    }
    if (g == 0) hs[0][hd] = f2h(h);
    __syncthreads();

    const ushort* gxb = gx2 + (size_t)b * TCc * G4_;
    ushort* hb = hbuf + (size_t)b * T_ * H_ + (size_t)t0 * H_;

    ushort cg = gxb[tid];    // this (hd,g)'s input-gate term, step 0

    for (int tl = 0; tl < TCc; ++tl) {
        // prefetch next step's gate term (coalesced 2B/lane; hidden)
        const int tn = (tl + 1 < TCc) ? tl + 1 : tl;
        ushort ng = gxb[(size_t)tn * G4_ + tid];

        const ushort* hsr = hs[tl & 1];
        float a = 0.f;
#pragma unroll
        for (int kc = 0; kc < 32; ++kc) {
            uint4 hq = *(const uint4*)(hsr + kc * 8);   // wave-uniform bcast
            a = fdot2(wv[kc * 4 + 0], hq.x, a);
            a = fdot2(wv[kc * 4 + 1], hq.y, a);
            a = fdot2(wv[kc * 4 + 2], hq.z, a);
            a = fdot2(wv[kc * 4 + 3], hq.w, a);
        }
        a += h2f(cg);

        // gather the quad's 4 gates: s_k holds gate g^k
        float s1 = __shfl_xor(a, 1);
        float s2 = __shfl_xor(a, 2);
        float s3 = __shfl_xor(a, 3);
        float ai = (g == 0) ? a : ((g == 1) ? s1 : ((g == 2) ? s2 : s3));
        float af = (g == 1) ? a : ((g == 0) ? s1 : ((g == 3) ? s2 : s3));
        float ag = (g == 2) ? a : ((g == 3) ? s1 : ((g == 0) ? s2 : s3));
        float ao = (g == 3) ? a : ((g == 2) ? s1 : ((g == 1) ? s2 : s3));

        // elementwise cell update (all 4 lanes of the quad, redundant)
        float si = __builtin_amdgcn_rcpf(1.f + __expf(-ai));
        float sf = __builtin_amdgcn_rcpf(1.f + __expf(-af));
        float so = __builtin_amdgcn_rcpf(1.f + __expf(-ao));
        float eg = __expf(2.f * ag);
        float tg = (eg - 1.f) * __builtin_amdgcn_rcpf(eg + 1.f);
        c = sf * c + si * tg;
        float ec = __expf(2.f * c);
        float tc = (ec - 1.f) * __builtin_amdgcn_rcpf(ec + 1.f);
        h = so * tc;

        if (g == 0) {
            ushort hh = f2h(h);
            hs[(tl + 1) & 1][hd] = hh;    // write OTHER buffer
            hb[(size_t)tl * H_ + hd] = hh;
        }
        cg = ng;
        __syncthreads();                  // single barrier per step
    }

    if (g == 0) {
        state[b * H_ + hd]           = c;
        state[B_ * H_ + b * H_ + hd] = h;
    }
}

// ---------------------------------------------------------------------------
// out[b,t] = sum_hd h[b,t,hd] * Wo[hd] + bo.  Single launch over full T.
// ---------------------------------------------------------------------------
__global__ __launch_bounds__(256) void proj_kernel(
    const ushort* __restrict__ hbuf, const float* __restrict__ Wo,
    const float* __restrict__ bo, float* __restrict__ out) {

    const int lane = threadIdx.x & 63;
    const int wid  = blockIdx.x * 4 + (threadIdx.x >> 6);
    const int nw   = gridDim.x * 4;
    const int rows = B_ * T_;

    float4 w = *(const float4*)(Wo + lane * 4);
    const float bov = bo[0];

    for (int r = wid; r < rows; r += nw) {
        const ushort* hp = hbuf + (size_t)r * H_ + lane * 4;
        ushort4 u = *(const ushort4*)hp;
        float p = h2f(u.x) * w.x + h2f(u.y) * w.y + h2f(u.z) * w.z + h2f(u.w) * w.w;
#pragma unroll
        for (int m = 1; m < 64; m <<= 1) p += __shfl_xor(p, m, 64);
        if (lane == 0) out[r] = p + bov;
    }
}

// ---------------------------------------------------------------------------
extern "C" void kernel_launch(void* const* d_in, const int* in_sizes, int n_in,
                              void* d_out, int out_size, void* d_ws, size_t ws_size,
                              hipStream_t stream) {
    const float* x   = (const float*)d_in[0];
    const float* Wih = (const float*)d_in[1];
    const float* Whh = (const float*)d_in[2];
    const float* bih = (const float*)d_in[3];
    const float* bhh = (const float*)d_in[4];
    const float* Wo  = (const float*)d_in[5];
    const float* bo  = (const float*)d_in[6];
    float* out = (float*)d_out;

    char* ws = (char*)d_ws;
    ushort* wpk2  = (ushort*)ws;                              // 512 KB
    float*  state = (float*)(ws + 512 * 1024);                // 128 KB
    ushort* hbuf  = (ushort*)(ws + 640 * 1024);               // 64 MB full-T h
    const size_t hbuf_bytes = (size_t)B_ * T_ * H_ * 2;
    char*   dyn   = ws + 640 * 1024 + hbuf_bytes;             // gx2 chunks

    size_t fixed = 640 * 1024 + hbuf_bytes;
    size_t avail = (ws_size > fixed) ? ws_size - fixed : 0;
    long long tcmax = (long long)(avail / ((size_t)B_ * G4_ * 2));
    // Cap chunks at 512 steps so gx2 (64MB) + hbuf stay L3-resident.
    int TC = (tcmax > 512) ? 512 : (int)tcmax;
    TC &= ~63;               // multiple of 64
    if (TC < 64) TC = 64;    // minimum viable chunk

    repack_kernel<<<1024, 256, 0, stream>>>(Whh, wpk2);

    for (int t0 = 0; t0 < T_; t0 += TC) {
        int TCc = (T_ - t0 < TC) ? (T_ - t0) : TC;
        ushort* gxb = (ushort*)dyn;
        dim3 g1((B_ * TCc) / 32, 4);
        gx_kernel<<<g1, 256, 0, stream>>>(x, Wih, bih, bhh, gxb, t0, TCc);
        lstm_kernel<<<B_, 1024, 0, stream>>>(wpk2, gxb, hbuf, state, TCc, t0, t0 == 0 ? 1 : 0);
    }
    proj_kernel<<<512, 256, 0, stream>>>(hbuf, Wo, bo, out);
    (void)in_sizes; (void)n_in; (void)out_size;
}

// Round 18
// 2997.449 us; speedup vs baseline: 3.3764x; 2.7372x over previous
//
#include <hip/hip_runtime.h>
#include <hip/hip_fp16.h>

#define B_  64
#define T_  2048
#define I_  64
#define H_  256
#define G4_ 1024   // 4*H

typedef _Float16 h2v __attribute__((ext_vector_type(2)));

__device__ __forceinline__ float fdot2(uint32_t a, uint32_t b, float c) {
#if __has_builtin(__builtin_amdgcn_fdot2)
    return __builtin_amdgcn_fdot2(__builtin_bit_cast(h2v, a), __builtin_bit_cast(h2v, b), c, false);
#else
    h2v ha = __builtin_bit_cast(h2v, a), hb = __builtin_bit_cast(h2v, b);
    return c + (float)ha.x * (float)hb.x + (float)ha.y * (float)hb.y;
#endif
}

__device__ __forceinline__ ushort f2h(float v) {
    return __builtin_bit_cast(ushort, (_Float16)v);
}
__device__ __forceinline__ float h2f(ushort v) {
    return (float)__builtin_bit_cast(_Float16, v);
}

// ---------------------------------------------------------------------------
// Repack W_hh fp32 [1024][256] -> f16 wpk[g][kc][h][j]  (g=gate, kc=K/8 chunk,
// h=hdim 0..255, j=0..7).  (r8/r14 layout -- proven.)
// ---------------------------------------------------------------------------
__global__ void repack_kernel(const float* __restrict__ Whh, ushort* __restrict__ wpk) {
    int o  = blockIdx.x * 256 + threadIdx.x;   // 0 .. 262143
    int j  = o & 7;
    int h  = (o >> 3) & 255;
    int kc = (o >> 11) & 31;
    int g  = o >> 16;
    float v = Whh[(g * 256 + h) * 256 + kc * 8 + j];
    wpk[o] = f2h(v);
}

// ---------------------------------------------------------------------------
// gx2 = x @ W_ih^T + b_ih + b_hh, TRANSPOSED f16 layout [bt][hd][gate].
// Packed-f16 fdot2 inner loop (r14 -- proven).  grid = ((64*TCc)/32, 4).
// ---------------------------------------------------------------------------
__global__ __launch_bounds__(256) void gx_kernel(
    const float* __restrict__ x, const float* __restrict__ Wih,
    const float* __restrict__ bih, const float* __restrict__ bhh,
    ushort* __restrict__ gx2, int t0, int TCc) {

    __shared__ uint32_t xsp[32][32];            // 32 bt-rows x 32 f16-pairs
    const int bt0 = blockIdx.x * 32;
    const int gq  = blockIdx.y;                 // gate 0..3 (i,f,g,o)
    const int row = gq * 256 + threadIdx.x;     // W_ih row

    for (int i = threadIdx.x; i < 512; i += 256) {
        int r  = i >> 4, c4 = i & 15;
        int bt = bt0 + r;
        int b  = bt / TCc;
        int tl = bt - b * TCc;
        float4 v = *(const float4*)(&x[(((size_t)b * T_) + t0 + tl) * I_ + c4 * 4]);
        xsp[r][c4 * 2 + 0] = (uint32_t)f2h(v.x) | ((uint32_t)f2h(v.y) << 16);
        xsp[r][c4 * 2 + 1] = (uint32_t)f2h(v.z) | ((uint32_t)f2h(v.w) << 16);
    }
    __syncthreads();

    uint32_t wp[32];
#pragma unroll
    for (int k = 0; k < 32; ++k) {
        float a = Wih[row * I_ + 2 * k];
        float b = Wih[row * I_ + 2 * k + 1];
        wp[k] = (uint32_t)f2h(a) | ((uint32_t)f2h(b) << 16);
    }
    const float bias = bih[row] + bhh[row];

    for (int i = 0; i < 32; ++i) {
        float acc = bias;
#pragma unroll
        for (int k4 = 0; k4 < 8; ++k4) {
            uint4 xq = *(const uint4*)(&xsp[i][k4 * 4]);   // wave-uniform bcast
            acc = fdot2(wp[k4 * 4 + 0], xq.x, acc);
            acc = fdot2(wp[k4 * 4 + 1], xq.y, acc);
            acc = fdot2(wp[k4 * 4 + 2], xq.z, acc);
            acc = fdot2(wp[k4 * 4 + 3], xq.w, acc);
        }
        gx2[((size_t)(bt0 + i) * 256 + threadIdx.x) * 4 + gq] = f2h(acc);
    }
}

// ---------------------------------------------------------------------------
// Persistent per-batch LSTM -- round-14 champion structure (731 us/chunk),
// CONSOLIDATED.  The design space is fully mapped: MFMA matvec 890-960,
// cross-CU 2500, 1024-thr gate-parallel 2000, full-reg 1740 -- all lose to
// this 512-thr fdot2 balance (weights 200 dw = 128 arch + AGPR; o-gate
// kc 0..13 streamed from LDS; 2 barriers/step).
// r18 micro-fix: o-stream LDS layout [q][kc][hd] so each thread's 14 reads
// span 53 KB < the 64 KB ds_read imm-offset limit (r14's [kc'][q][hd]
// spanned 106 KB -> per-read address VALU).  All reads fold to base+imm.
// ---------------------------------------------------------------------------
__global__ __launch_bounds__(512, 1)
void lstm_kernel(
    const ushort* __restrict__ wpk, const ushort* __restrict__ gx2,
    ushort* __restrict__ hbuf,     // [B][T][H] f16 (full-T)
    float* __restrict__ state,     // [2][64][256]: c then h
    int TCc, int t0, int first) {

    __shared__ __align__(16) ushort wg4[2 * 14 * 256 * 8]; // o-gate [q][kc][hd][8]
    __shared__ __align__(16) ushort hs[256];               // h(t-1) as f16
    __shared__ __align__(16) float pex[256][4];            // q=1 -> q=0 partials

    const int tid   = threadIdx.x;
    const int hd    = tid & 255;       // owned h-dim
    const int q     = tid >> 8;        // K-half: 0 -> kc 0..15, 1 -> kc 16..31
    const int kbase = q << 4;
    const int b     = blockIdx.x;
    const bool q0   = (q == 0);

    // --- preload i/f/g gate half-rows into registers (16B/lane, coalesced) ---
    uint32_t wi[64], wf[64], wg[64];
#pragma unroll
    for (int k = 0; k < 16; ++k) {
        uint4 v = *(const uint4*)(wpk + (size_t)(0 * 32 + kbase + k) * 2048 + hd * 8);
        wi[k * 4 + 0] = v.x; wi[k * 4 + 1] = v.y; wi[k * 4 + 2] = v.z; wi[k * 4 + 3] = v.w;
    }
#pragma unroll
    for (int k = 0; k < 16; ++k) {
        uint4 v = *(const uint4*)(wpk + (size_t)(1 * 32 + kbase + k) * 2048 + hd * 8);
        wf[k * 4 + 0] = v.x; wf[k * 4 + 1] = v.y; wf[k * 4 + 2] = v.z; wf[k * 4 + 3] = v.w;
    }
#pragma unroll
    for (int k = 0; k < 16; ++k) {
        uint4 v = *(const uint4*)(wpk + (size_t)(2 * 32 + kbase + k) * 2048 + hd * 8);
        wg[k * 4 + 0] = v.x; wg[k * 4 + 1] = v.y; wg[k * 4 + 2] = v.z; wg[k * 4 + 3] = v.w;
    }
    // --- o-gate: kc 0..13 -> LDS [q][kc][hd][8]; kc 14..15 -> registers ---
#pragma unroll
    for (int k = 0; k < 14; ++k) {
        uint4 v = *(const uint4*)(wpk + (size_t)(3 * 32 + kbase + k) * 2048 + hd * 8);
        *(uint4*)(wg4 + ((q * 14 + k) * 256 + hd) * 8) = v;
    }
    uint32_t wo_r[8];
#pragma unroll
    for (int k = 0; k < 2; ++k) {
        uint4 v = *(const uint4*)(wpk + (size_t)(3 * 32 + kbase + 14 + k) * 2048 + hd * 8);
        wo_r[k * 4 + 0] = v.x; wo_r[k * 4 + 1] = v.y; wo_r[k * 4 + 2] = v.z; wo_r[k * 4 + 3] = v.w;
    }
    // per-thread o-stream base: 14 reads at +k*4096B (all imm-foldable)
    const ushort* wob = wg4 + (q * 14 * 256 + hd) * 8;

    float c = 0.f, h = 0.f;
    if (q0) {
        if (!first) {
            c = state[b * H_ + hd];
            h = state[B_ * H_ + b * H_ + hd];
        }
        hs[hd] = f2h(h);
    }
    __syncthreads();

    const ushort* gxb = gx2 + (size_t)b * TCc * G4_;
    ushort* hb = hbuf + (size_t)b * T_ * H_ + (size_t)t0 * H_;

    ushort4 cg;
    if (q0) cg = *(const ushort4*)(gxb + (size_t)0 * G4_ + hd * 4);

    for (int tl = 0; tl < TCc; ++tl) {
        // prefetch next step's gates (q0 only; hidden under the dot loop)
        ushort4 ng;
        if (q0) {
            const int tn = (tl + 1 < TCc) ? tl + 1 : tl;
            ng = *(const ushort4*)(gxb + (size_t)tn * G4_ + hd * 4);
        }

        float ai = 0.f, af = 0.f, agv = 0.f, ao = 0.f;

        // --- kc 0..13 of this half: o-weights stream from LDS (base+imm) ---
#pragma unroll
        for (int k = 0; k < 14; ++k) {
            const int kc = kbase + k;
            uint4 hq = *(const uint4*)(hs + kc * 8);           // bcast
            uint4 wo = *(const uint4*)(wob + k * 2048);        // stream, imm ofs
            ai  = fdot2(wi[k * 4 + 0], hq.x, ai);
            ai  = fdot2(wi[k * 4 + 1], hq.y, ai);
            ai  = fdot2(wi[k * 4 + 2], hq.z, ai);
            ai  = fdot2(wi[k * 4 + 3], hq.w, ai);
            af  = fdot2(wf[k * 4 + 0], hq.x, af);
            af  = fdot2(wf[k * 4 + 1], hq.y, af);
            af  = fdot2(wf[k * 4 + 2], hq.z, af);
            af  = fdot2(wf[k * 4 + 3], hq.w, af);
            agv = fdot2(wg[k * 4 + 0], hq.x, agv);
            agv = fdot2(wg[k * 4 + 1], hq.y, agv);
            agv = fdot2(wg[k * 4 + 2], hq.z, agv);
            agv = fdot2(wg[k * 4 + 3], hq.w, agv);
            ao  = fdot2(wo.x, hq.x, ao);
            ao  = fdot2(wo.y, hq.y, ao);
            ao  = fdot2(wo.z, hq.z, ao);
            ao  = fdot2(wo.w, hq.w, ao);
        }
        // --- kc 14..15 of this half: o-weights from registers ---
#pragma unroll
        for (int k = 14; k < 16; ++k) {
            const int kc = kbase + k;
            const int r  = (k - 14) * 4;
            uint4 hq = *(const uint4*)(hs + kc * 8);
            ai  = fdot2(wi[k * 4 + 0], hq.x, ai);
            ai  = fdot2(wi[k * 4 + 1], hq.y, ai);
            ai  = fdot2(wi[k * 4 + 2], hq.z, ai);
            ai  = fdot2(wi[k * 4 + 3], hq.w, ai);
            af  = fdot2(wf[k * 4 + 0], hq.x, af);
            af  = fdot2(wf[k * 4 + 1], hq.y, af);
            af  = fdot2(wf[k * 4 + 2], hq.z, af);
            af  = fdot2(wf[k * 4 + 3], hq.w, af);
            agv = fdot2(wg[k * 4 + 0], hq.x, agv);
            agv = fdot2(wg[k * 4 + 1], hq.y, agv);
            agv = fdot2(wg[k * 4 + 2], hq.z, agv);
            agv = fdot2(wg[k * 4 + 3], hq.w, agv);
            ao  = fdot2(wo_r[r + 0], hq.x, ao);
            ao  = fdot2(wo_r[r + 1], hq.y, ao);
            ao  = fdot2(wo_r[r + 2], hq.z, ao);
            ao  = fdot2(wo_r[r + 3], hq.w, ao);
        }

        if (!q0) {
            float4 p; p.x = ai; p.y = af; p.z = agv; p.w = ao;
            *(float4*)(&pex[hd][0]) = p;
        }
        __syncthreads();

        if (q0) {
            float4 px = *(const float4*)(&pex[hd][0]);
            ai += px.x; af += px.y; agv += px.z; ao += px.w;

            ai += h2f(cg.x); af += h2f(cg.y); agv += h2f(cg.z); ao += h2f(cg.w);

            float si = __builtin_amdgcn_rcpf(1.f + __expf(-ai));
            float sf = __builtin_amdgcn_rcpf(1.f + __expf(-af));
            float so = __builtin_amdgcn_rcpf(1.f + __expf(-ao));
            float eg = __expf(2.f * agv);
            float tg = (eg - 1.f) * __builtin_amdgcn_rcpf(eg + 1.f);
            c = sf * c + si * tg;
            float ec = __expf(2.f * c);
            float tc = (ec - 1.f) * __builtin_amdgcn_rcpf(ec + 1.f);
            h = so * tc;

            ushort hh = f2h(h);
            hs[hd] = hh;
            hb[(size_t)tl * H_ + hd] = hh;
            cg = ng;
        }
        __syncthreads();
    }

    if (q0) {
        state[b * H_ + hd]           = c;
        state[B_ * H_ + b * H_ + hd] = h;
    }
}

// ---------------------------------------------------------------------------
// out[b,t] = sum_hd h[b,t,hd] * Wo[hd] + bo.  Single launch over full T.
// ---------------------------------------------------------------------------
__global__ __launch_bounds__(256) void proj_kernel(
    const ushort* __restrict__ hbuf, const float* __restrict__ Wo,
    const float* __restrict__ bo, float* __restrict__ out) {

    const int lane = threadIdx.x & 63;
    const int wid  = blockIdx.x * 4 + (threadIdx.x >> 6);
    const int nw   = gridDim.x * 4;
    const int rows = B_ * T_;

    float4 w = *(const float4*)(Wo + lane * 4);
    const float bov = bo[0];

    for (int r = wid; r < rows; r += nw) {
        const ushort* hp = hbuf + (size_t)r * H_ + lane * 4;
        ushort4 u = *(const ushort4*)hp;
        float p = h2f(u.x) * w.x + h2f(u.y) * w.y + h2f(u.z) * w.z + h2f(u.w) * w.w;
#pragma unroll
        for (int m = 1; m < 64; m <<= 1) p += __shfl_xor(p, m, 64);
        if (lane == 0) out[r] = p + bov;
    }
}

// ---------------------------------------------------------------------------
extern "C" void kernel_launch(void* const* d_in, const int* in_sizes, int n_in,
                              void* d_out, int out_size, void* d_ws, size_t ws_size,
                              hipStream_t stream) {
    const float* x   = (const float*)d_in[0];
    const float* Wih = (const float*)d_in[1];
    const float* Whh = (const float*)d_in[2];
    const float* bih = (const float*)d_in[3];
    const float* bhh = (const float*)d_in[4];
    const float* Wo  = (const float*)d_in[5];
    const float* bo  = (const float*)d_in[6];
    float* out = (float*)d_out;

    char* ws = (char*)d_ws;
    ushort* wpk   = (ushort*)ws;                              // 512 KB
    float*  state = (float*)(ws + 512 * 1024);                // 128 KB
    ushort* hbuf  = (ushort*)(ws + 640 * 1024);               // 64 MB full-T h
    const size_t hbuf_bytes = (size_t)B_ * T_ * H_ * 2;
    char*   dyn   = ws + 640 * 1024 + hbuf_bytes;             // gx2 chunks

    size_t fixed = 640 * 1024 + hbuf_bytes;
    size_t avail = (ws_size > fixed) ? ws_size - fixed : 0;
    long long tcmax = (long long)(avail / ((size_t)B_ * G4_ * 2));
    // TC=1024: gx2 (128MB) + hbuf (64MB) = 192MB < 256MB L3 (r3 lesson), and
    // halves launch count vs TC=512.
    int TC = (tcmax > 1024) ? 1024 : (int)tcmax;
    TC &= ~63;               // multiple of 64
    if (TC < 64) TC = 64;    // minimum viable chunk

    repack_kernel<<<1024, 256, 0, stream>>>(Whh, wpk);

    for (int t0 = 0; t0 < T_; t0 += TC) {
        int TCc = (T_ - t0 < TC) ? (T_ - t0) : TC;
        ushort* gxb = (ushort*)dyn;
        dim3 g1((B_ * TCc) / 32, 4);
        gx_kernel<<<g1, 256, 0, stream>>>(x, Wih, bih, bhh, gxb, t0, TCc);
        lstm_kernel<<<B_, 512, 0, stream>>>(wpk, gxb, hbuf, state, TCc, t0, t0 == 0 ? 1 : 0);
    }
    proj_kernel<<<512, 256, 0, stream>>>(hbuf, Wo, bo, out);
    (void)in_sizes; (void)n_in; (void)out_size;
}